// Round 2
// baseline (383.881 us; speedup 1.0000x reference)
//
#include <hip/hip_runtime.h>

// LIF forward recurrence, bit-exact vs the numpy fp32 reference.
//
// Reference per step (exact op order, correctly rounded, no contraction):
//   th   = 1 + 1.5*a
//   v    = (v - v/20) + I_t
//   s    = (v >= th) ? 1 : 0        // STE forward == s_hard exactly (Sterbenz)
//   snum += s                       // exact {0,1} integer cumsum
//   v    = s ? -0.5 : v
//   a    = (a - a/100) + s
//
// R1: LDS 64x64 tile transpose killed 3x HBM write amplification.
// R2: Markstein 3-op constant division (provably == __fdiv_rn for d=20,100).
// R4: producer/consumer wave specialization.
// R5: lgkm-only barriers.
// R6: XOR-swizzled b128 LDS layout + speculative-decay recurrence on vn.
// R7: quad-buffered spike tiles, one barrier per 2 tiles.
// R8: rocprof shows lif_fwd absent from the top-5 dispatches (all five are
// 166us 1-GiB harness poison fills) => kernel slice is ~45us of the 377us
// graph. The helper wave was the critical wave: per pair it ran 64 ds_read +
// a 512-cycle SERIAL carry chain + 32 ds_write + 64 stores. Changes:
// (a) cumsum moved into the compute wave (carry += s, 1 op/step, parallel
// across lanes) writing a second LDS stream, making helper tiles stateless;
// (b) TWO helper waves, one tile each per pair (2x store queues, half the
// per-helper LDS work, no carry handoff); (c) lif_step shaved 17 -> 15 core
// ops (select-then-add for vn; a' = rn(ap + s), both provably bit-identical),
// paying for the carry add. LDS 128 KB (static, within gfx950's 160 KiB;
// cf. the 128 KiB m201 GEMM example), still 1 block/CU.
// R9 (this): R8 bench died with "container failed twice" (infra, no kernel
// verdict: no passed/absmax payload). Audit found no deadlock (barrier is
// wave-uniform), no LDS overrun, no WAR race (parity-disjoint sets +
// lgkmcnt(0) drain). Resubmitting R8 unchanged for a real measurement.

#define LIF_L  2048
#define TILE   64
#define NTILES (LIF_L / TILE)   // 32

// Compile-time, correctly rounded: rn(-0.5/20) and rn(-0.5 - that).
constexpr float kR20 = -0.5f / 20.0f;
constexpr float kC0  = -0.5f - kR20;

__device__ __forceinline__ void barrier_lds_only() {
    asm volatile("s_waitcnt lgkmcnt(0)\n\ts_barrier" ::: "memory");
}

// One step. vn = membrane AFTER input add (what the threshold sees).
// Inext = input of the NEXT step. Returns spike float {0,1}.
// 16 VALU ops incl. the snum cumsum:
//   cmp, cndmask(s), mul/fma/fma (div20), sub, cndmask(sel), add(vn),
//   add(carry), mul/fma/fma (div100), sub(ap), add(a), mul+add (th)
__device__ __forceinline__ float lif_step(float Inext, float& vn, float& a,
                                          float& th, float& carry) {
    bool fire = (vn >= th);
    float s = fire ? 1.0f : 0.0f;
    // no-spike decayed value: rn(vn - rn(vn/20)), Markstein div
    float q0 = __fmul_rn(vn, 0.05f);
    float r  = __fmaf_rn(-20.0f, q0, vn);
    float d  = __fmaf_rn(r, 0.05f, q0);        // == __fdiv_rn(vn, 20) for all vn
    float dec = __fsub_rn(vn, d);
    // select BEFORE the Inext add: rn(sel + Inext) is bitwise identical to the
    // old { ns = rn(dec+Inext); ss = rn(kC0+Inext); fire?ss:ns } form.
    float sel = fire ? kC0 : dec;
    vn = __fadd_rn(sel, Inext);
    // snum cumsum: exact, matches reference s_num = s_num + s order
    carry = __fadd_rn(carry, s);
    // a: ap = rn(a - rn(a/100)); a' = rn(ap + s) == fire ? rn(ap+1) : ap
    // (s is exactly 0.0f or 1.0f, rn(ap+0) == ap incl. +0 sign since ap >= 0)
    float qa = __fmul_rn(a, 0.01f);
    float ra = __fmaf_rn(-100.0f, qa, a);
    float da = __fmaf_rn(ra, 0.01f, qa);       // == __fdiv_rn(a, 100) for all a
    float ap = __fsub_rn(a, da);
    a = __fadd_rn(ap, s);
    th = __fadd_rn(1.0f, __fmul_rn(1.5f, a));  // reference order: mul then add
    return s;
}

// Swizzled LDS float index for (row, 16B-group g): aligned b128, conflict-free.
__device__ __forceinline__ int sw_idx(int row, int g) {
    return row * 64 + (((g) ^ (row & 15)) << 2);
}

__global__ __launch_bounds__(192, 1) void lif_fwd(const float* __restrict__ I,
                                                  float* __restrict__ spikes,
                                                  float* __restrict__ series) {
    __shared__ float sp_tile[4][64 * 64];      // quad-buffered spike tiles (64 KB)
    __shared__ float se_tile[4][64 * 64];      // quad-buffered series tiles (64 KB)

    const int tid  = threadIdx.x;
    const int wave = tid >> 6;                 // 0 = compute, 1/2 = helpers
    const int lane = tid & 63;
    const int row0 = blockIdx.x * 64;

    const float4* __restrict__ I4 =
        reinterpret_cast<const float4*>(I + (size_t)(row0 + lane) * LIF_L);

    // compute-wave state
    float vn = 0.0f, a = 0.0f, th = 1.0f, carry = 0.0f;
    float4 bufA[16], bufB[16];

    if (wave == 0) {
        #pragma unroll
        for (int i = 0; i < 16; ++i) bufA[i] = I4[i];
        #pragma unroll
        for (int i = 0; i < 16; ++i) bufB[i] = I4[16 + i];
    }

    auto compute_tile = [&](const float4* buf, float nx0, float* sp, float* se) {
        #pragma unroll
        for (int c = 0; c < 16; ++c) {
            float4 in = buf[c];
            float nxt = (c < 15) ? buf[c + 1].x : nx0;
            float4 os, oc;
            os.x = lif_step(in.y, vn, a, th, carry); oc.x = carry;
            os.y = lif_step(in.z, vn, a, th, carry); oc.y = carry;
            os.z = lif_step(in.w, vn, a, th, carry); oc.z = carry;
            os.w = lif_step(nxt,  vn, a, th, carry); oc.w = carry;
            *reinterpret_cast<float4*>(&sp[sw_idx(lane, c)]) = os;  // ds_write_b128
            *reinterpret_cast<float4*>(&se[sw_idx(lane, c)]) = oc;  // ds_write_b128
        }
    };

    // Stateless flush: transposed coalesced stores, instr i covers 4 rows x 256 B.
    auto flush_tile = [&](int tkt, const float* sp, const float* se) {
        const size_t colbase = (size_t)tkt * TILE;
        #pragma unroll
        for (int i = 0; i < 16; ++i) {
            int row = i * 4 + (lane >> 4);
            int g   = lane & 15;
            int ix  = sw_idx(row, g);
            float4 vs = *reinterpret_cast<const float4*>(&sp[ix]);
            float4 ve = *reinterpret_cast<const float4*>(&se[ix]);
            size_t gaddr = (size_t)(row0 + row) * LIF_L + colbase + (size_t)g * 4;
            *reinterpret_cast<float4*>(spikes + gaddr) = vs;
            *reinterpret_cast<float4*>(series + gaddr) = ve;
        }
    };

    // init: vn_0 = rn(rn(0 - rn(0/20)) + I_0) = I_0 exactly
    if (wave == 0) vn = bufA[0].x;

    // Pair loop: iteration p computes tiles {2p, 2p+1} into buffer set
    // {(2p)&3, (2p+1)&3}; helpers consume pair p-1 (the other, disjoint set):
    // wave1 flushes tile 2p-2, wave2 flushes tile 2p-1. One barrier per pair.
    for (int p = 0; p < NTILES / 2; ++p) {
        const int kt = 2 * p;
        if (wave == 0) {
            compute_tile(bufA, bufB[0].x, sp_tile[kt & 3], se_tile[kt & 3]);
            if (kt + 2 < NTILES) {
                #pragma unroll
                for (int i = 0; i < 16; ++i) bufA[i] = I4[(kt + 2) * 16 + i];
            }
            float nx0 = (kt + 2 < NTILES) ? bufA[0].x : 0.0f;
            compute_tile(bufB, nx0, sp_tile[(kt + 1) & 3], se_tile[(kt + 1) & 3]);
            if (kt + 3 < NTILES) {
                #pragma unroll
                for (int i = 0; i < 16; ++i) bufB[i] = I4[(kt + 3) * 16 + i];
            }
        } else if (p > 0) {
            if (wave == 1) {
                flush_tile(kt - 2, sp_tile[(kt - 2) & 3], se_tile[(kt - 2) & 3]);
            } else {
                flush_tile(kt - 1, sp_tile[(kt - 1) & 3], se_tile[(kt - 1) & 3]);
            }
        }
        barrier_lds_only();
    }
    // tail: last pair (tiles 30, 31 live in buffer sets 2, 3)
    if (wave == 1) {
        flush_tile(NTILES - 2, sp_tile[(NTILES - 2) & 3], se_tile[(NTILES - 2) & 3]);
    } else if (wave == 2) {
        flush_tile(NTILES - 1, sp_tile[(NTILES - 1) & 3], se_tile[(NTILES - 1) & 3]);
    }
}

extern "C" void kernel_launch(void* const* d_in, const int* in_sizes, int n_in,
                              void* d_out, int out_size, void* d_ws, size_t ws_size,
                              hipStream_t stream) {
    const float* I = (const float*)d_in[0];
    const int B = in_sizes[0] / LIF_L;                  // 16384
    float* spikes = (float*)d_out;                      // (B, L)
    float* series = (float*)d_out + (size_t)B * LIF_L;  // (B, L)

    const int threads = 192;                            // 3 waves: compute + 2 helpers
    const int blocks = B / 64;                          // 256 blocks, 64 rows each
    lif_fwd<<<blocks, threads, 0, stream>>>(I, spikes, series);
}

// Round 3
// 375.381 us; speedup vs baseline: 1.0226x; 1.0226x over previous
//
#include <hip/hip_runtime.h>

// LIF forward recurrence, bit-exact vs the numpy fp32 reference.
//
// Reference per step (exact op order, correctly rounded, no contraction):
//   th   = 1 + 1.5*a
//   v    = (v - v/20) + I_t
//   s    = (v >= th) ? 1 : 0        // STE forward == s_hard exactly (Sterbenz)
//   snum += s                       // exact {0,1} integer cumsum
//   v    = s ? -0.5 : v
//   a    = (a - a/100) + s
//
// R1: LDS 64x64 tile transpose killed 3x HBM write amplification.
// R2: Markstein 3-op constant division (provably == __fdiv_rn for d=20,100).
// R4: producer/consumer wave specialization.
// R5: lgkm-only barriers.
// R6: XOR-swizzled b128 LDS layout + speculative-decay recurrence on vn.
// R7: quad-buffered spike tiles, one barrier per 2 tiles.
// R8: compute-side cumsum, stateless 2-helper flush, 15-op lif_step.
// R9: resubmit after infra failure. Result: NEUTRAL vs R7 (slice ~46 us vs
// ~44 us, inside fill noise) => helper was NOT the critical wave. Revised
// model: the compute wave's serial issue stream IS the floor: 2048 steps x
// 16 VALU x 2 cyc = 27.3 us + ds/load issue ~= 29 us vs ~46 us slice.
// Output writes are L3-absorbed (390 MB in 46 us = 8.5 TB/s apparent >
// HBM peak), so memory is not the binding constraint; instructions are.
// R10 (this): packed-f32 dual issue. vn-decay and a-decay share the same
// 4-op Markstein skeleton with different constants -> pack x=(vn,a) in a
// VGPR pair, run both decays with v_pk_{mul,fma}_f32 (per-component IEEE
// rn == scalar ops, bit-exact by construction), and fuse the state update
// (vn',a') = (sel,ap) + (Inext,s) into one v_pk_add_f32. 16 -> ~12 issued
// ops/step, compute floor 29 -> ~23 us. Emitted via float2 ext-vector +
// __builtin_elementwise_fma (clang lowers to pk ops on CDNA; worst case
// scalarizes -> provably neutral). Everything else unchanged from R8.

#define LIF_L  2048
#define TILE   64
#define NTILES (LIF_L / TILE)   // 32

typedef float f32x2 __attribute__((ext_vector_type(2)));

// Compile-time, correctly rounded: rn(-0.5/20) and rn(-0.5 - that).
constexpr float kR20 = -0.5f / 20.0f;
constexpr float kC0  = -0.5f - kR20;

__device__ __forceinline__ void barrier_lds_only() {
    asm volatile("s_waitcnt lgkmcnt(0)\n\ts_barrier" ::: "memory");
}

// One step. x = (vn, a): vn = membrane AFTER input add (what the threshold
// sees), a = adaptation. Inext = input of the NEXT step. Returns spike {0,1}.
//
// Bit-exactness vs the proven scalar version:
//   q   = x*C1                    : per-elem rn mul == {__fmul_rn(vn,.05), __fmul_rn(a,.01)}
//   r   = fma(C2,q,x)             : exact remainders {fma(-20,q0,vn), fma(-100,qa,a)}
//   d   = fma(r,C1,q)             : Markstein => d == {__fdiv_rn(vn,20), __fdiv_rn(a,100)}
//   dec = fma(d,-1,x)             : exact product => single-rounded rn(x-d) == __fsub_rn
//   dec.x = fire ? kC0 : dec.x    : select-before-add (distributes over final rn add)
//   x'  = dec + (Inext, s)        : {rn(sel+Inext), rn(ap+s)}; s in {0,1}, ap>=0
//   th  = rn(1 + rn(1.5*a'))      : reference order mul-then-add
__device__ __forceinline__ float lif_step(float Inext, f32x2& x, float& th,
                                          float& carry) {
    const f32x2 C1 = {0.05f, 0.01f};
    const f32x2 C2 = {-20.0f, -100.0f};
    const f32x2 M1 = {-1.0f, -1.0f};
    bool fire = (x.x >= th);
    float s = fire ? 1.0f : 0.0f;
    f32x2 q   = x * C1;                              // v_pk_mul_f32
    f32x2 r   = __builtin_elementwise_fma(C2, q, x); // v_pk_fma_f32
    f32x2 d   = __builtin_elementwise_fma(r, C1, q); // v_pk_fma_f32 (exact divs)
    f32x2 dec = __builtin_elementwise_fma(d, M1, x); // v_pk_fma_f32 (= x - d)
    dec.x = fire ? kC0 : dec.x;                      // cndmask on low half
    f32x2 t = {Inext, s};
    x = dec + t;                                     // v_pk_add_f32
    carry = __fadd_rn(carry, s);                     // exact {0,1} cumsum
    th = __fadd_rn(1.0f, __fmul_rn(1.5f, x.y));      // reference order
    return s;
}

// Swizzled LDS float index for (row, 16B-group g): aligned b128, conflict-free.
__device__ __forceinline__ int sw_idx(int row, int g) {
    return row * 64 + (((g) ^ (row & 15)) << 2);
}

__global__ __launch_bounds__(192, 1) void lif_fwd(const float* __restrict__ I,
                                                  float* __restrict__ spikes,
                                                  float* __restrict__ series) {
    __shared__ float sp_tile[4][64 * 64];      // quad-buffered spike tiles (64 KB)
    __shared__ float se_tile[4][64 * 64];      // quad-buffered series tiles (64 KB)

    const int tid  = threadIdx.x;
    const int wave = tid >> 6;                 // 0 = compute, 1/2 = helpers
    const int lane = tid & 63;
    const int row0 = blockIdx.x * 64;

    const float4* __restrict__ I4 =
        reinterpret_cast<const float4*>(I + (size_t)(row0 + lane) * LIF_L);

    // compute-wave state: x = (vn, a) packed for v_pk_* dual issue
    f32x2 x = {0.0f, 0.0f};
    float th = 1.0f, carry = 0.0f;
    float4 bufA[16], bufB[16];

    if (wave == 0) {
        #pragma unroll
        for (int i = 0; i < 16; ++i) bufA[i] = I4[i];
        #pragma unroll
        for (int i = 0; i < 16; ++i) bufB[i] = I4[16 + i];
    }

    auto compute_tile = [&](const float4* buf, float nx0, float* sp, float* se) {
        #pragma unroll
        for (int c = 0; c < 16; ++c) {
            float4 in = buf[c];
            float nxt = (c < 15) ? buf[c + 1].x : nx0;
            float4 os, oc;
            os.x = lif_step(in.y, x, th, carry); oc.x = carry;
            os.y = lif_step(in.z, x, th, carry); oc.y = carry;
            os.z = lif_step(in.w, x, th, carry); oc.z = carry;
            os.w = lif_step(nxt,  x, th, carry); oc.w = carry;
            *reinterpret_cast<float4*>(&sp[sw_idx(lane, c)]) = os;  // ds_write_b128
            *reinterpret_cast<float4*>(&se[sw_idx(lane, c)]) = oc;  // ds_write_b128
        }
    };

    // Stateless flush: transposed coalesced stores, instr i covers 4 rows x 256 B.
    auto flush_tile = [&](int tkt, const float* sp, const float* se) {
        const size_t colbase = (size_t)tkt * TILE;
        #pragma unroll
        for (int i = 0; i < 16; ++i) {
            int row = i * 4 + (lane >> 4);
            int g   = lane & 15;
            int ix  = sw_idx(row, g);
            float4 vs = *reinterpret_cast<const float4*>(&sp[ix]);
            float4 ve = *reinterpret_cast<const float4*>(&se[ix]);
            size_t gaddr = (size_t)(row0 + row) * LIF_L + colbase + (size_t)g * 4;
            *reinterpret_cast<float4*>(spikes + gaddr) = vs;
            *reinterpret_cast<float4*>(series + gaddr) = ve;
        }
    };

    // init: vn_0 = rn(rn(0 - rn(0/20)) + I_0) = I_0 exactly; a_0 = 0
    if (wave == 0) x.x = bufA[0].x;

    // Pair loop: iteration p computes tiles {2p, 2p+1} into buffer set
    // {(2p)&3, (2p+1)&3}; helpers consume pair p-1 (the other, disjoint set):
    // wave1 flushes tile 2p-2, wave2 flushes tile 2p-1. One barrier per pair.
    for (int p = 0; p < NTILES / 2; ++p) {
        const int kt = 2 * p;
        if (wave == 0) {
            compute_tile(bufA, bufB[0].x, sp_tile[kt & 3], se_tile[kt & 3]);
            if (kt + 2 < NTILES) {
                #pragma unroll
                for (int i = 0; i < 16; ++i) bufA[i] = I4[(kt + 2) * 16 + i];
            }
            float nx0 = (kt + 2 < NTILES) ? bufA[0].x : 0.0f;
            compute_tile(bufB, nx0, sp_tile[(kt + 1) & 3], se_tile[(kt + 1) & 3]);
            if (kt + 3 < NTILES) {
                #pragma unroll
                for (int i = 0; i < 16; ++i) bufB[i] = I4[(kt + 3) * 16 + i];
            }
        } else if (p > 0) {
            if (wave == 1) {
                flush_tile(kt - 2, sp_tile[(kt - 2) & 3], se_tile[(kt - 2) & 3]);
            } else {
                flush_tile(kt - 1, sp_tile[(kt - 1) & 3], se_tile[(kt - 1) & 3]);
            }
        }
        barrier_lds_only();
    }
    // tail: last pair (tiles 30, 31 live in buffer sets 2, 3)
    if (wave == 1) {
        flush_tile(NTILES - 2, sp_tile[(NTILES - 2) & 3], se_tile[(NTILES - 2) & 3]);
    } else if (wave == 2) {
        flush_tile(NTILES - 1, sp_tile[(NTILES - 1) & 3], se_tile[(NTILES - 1) & 3]);
    }
}

extern "C" void kernel_launch(void* const* d_in, const int* in_sizes, int n_in,
                              void* d_out, int out_size, void* d_ws, size_t ws_size,
                              hipStream_t stream) {
    const float* I = (const float*)d_in[0];
    const int B = in_sizes[0] / LIF_L;                  // 16384
    float* spikes = (float*)d_out;                      // (B, L)
    float* series = (float*)d_out + (size_t)B * LIF_L;  // (B, L)

    const int threads = 192;                            // 3 waves: compute + 2 helpers
    const int blocks = B / 64;                          // 256 blocks, 64 rows each
    lif_fwd<<<blocks, threads, 0, stream>>>(I, spikes, series);
}